// Round 1
// baseline (364.753 us; speedup 1.0000x reference)
//
#include <hip/hip_runtime.h>

#define BB 8
#define HH 512
#define WW 1024
#define TILE 32
#define HALO 2
#define LW (TILE + 2*HALO)   // 36

__device__ __forceinline__ float sigm(float v) { return 1.0f / (1.0f + __expf(-v)); }

// bilinear sample of src (B,C,H,W) at (gx, gy), border-clamped indices
template<int C>
__device__ __forceinline__ void bilin(const float* __restrict__ src, int b,
                                      float gx, float gy, float out[C]) {
    float x0f = floorf(gx), y0f = floorf(gy);
    float ax = gx - x0f, ay = gy - y0f;
    int x0 = (int)x0f, y0 = (int)y0f;
    int x0i = min(max(x0, 0), WW - 1);
    int x1i = min(max(x0 + 1, 0), WW - 1);
    int y0i = min(max(y0, 0), HH - 1);
    int y1i = min(max(y0 + 1, 0), HH - 1);
    float w00 = (1.f - ay) * (1.f - ax), w01 = (1.f - ay) * ax;
    float w10 = ay * (1.f - ax), w11 = ay * ax;
#pragma unroll
    for (int c = 0; c < C; ++c) {
        const float* p = src + (size_t)(b * C + c) * (HH * WW);
        float v00 = p[y0i * WW + x0i];
        float v01 = p[y0i * WW + x1i];
        float v10 = p[y1i * WW + x0i];
        float v11 = p[y1i * WW + x1i];
        out[c] = w00 * v00 + w01 * v01 + w10 * v10 + w11 * v11;
    }
}

// One direction of _dir_terms, fully fused. Each block: 32x32 output tile.
// acc[0] += sum of (ALPHA*data + BETA*smooth + GAMMA*grad + MASK_COST*(1-mask) + DELTA*pen(d2)*mask)
// acc[1] += sum of per-pixel EPE (forward direction only)
template<bool EPE>
__global__ __launch_bounds__(256)
void dir_kernel(const float* __restrict__ flowa, const float* __restrict__ flowb,
                const float* __restrict__ imga, const float* __restrict__ imgb,
                const float* __restrict__ target, float* __restrict__ acc) {
    __shared__ float lds_w[3][LW][LW];  // warped imgb (0 outside image, like zero-pad)
    __shared__ float lds_a[3][LW][LW];  // imga        (0 outside image)
    __shared__ float red[8];

    const int b = blockIdx.z;
    const int tx0 = blockIdx.x * TILE;
    const int ty0 = blockIdx.y * TILE;
    const int tid = threadIdx.x;
    const size_t plane = (size_t)HH * WW;

    // ---- halo fill: warp imgb by flowa; stage imga ----
    for (int p = tid; p < LW * LW; p += 256) {
        int hy = p / LW, hx = p % LW;
        int gy = ty0 + hy - HALO, gx = tx0 + hx - HALO;
        float w[3] = {0.f, 0.f, 0.f};
        float a0 = 0.f, a1 = 0.f, a2 = 0.f;
        if (gx >= 0 && gx < WW && gy >= 0 && gy < HH) {
            size_t fi = (size_t)(b * 2) * plane + (size_t)gy * WW + gx;
            float fx = flowa[fi];
            float fy = flowa[fi + plane];
            bilin<3>(imgb, b, (float)gx + fx, (float)gy + fy, w);
            size_t ii = (size_t)(b * 3) * plane + (size_t)gy * WW + gx;
            a0 = imga[ii];
            a1 = imga[ii + plane];
            a2 = imga[ii + 2 * plane];
        }
        lds_w[0][hy][hx] = w[0]; lds_w[1][hy][hx] = w[1]; lds_w[2][hy][hx] = w[2];
        lds_a[0][hy][hx] = a0;   lds_a[1][hy][hx] = a1;   lds_a[2][hy][hx] = a2;
    }
    __syncthreads();

    float local = 0.f, lepe = 0.f;
    const float T0 = 1.f / 12.f, T1 = 2.f / 3.f;

#pragma unroll
    for (int i = 0; i < 4; ++i) {
        int p = i * 256 + tid;
        int ly = p >> 5, lx = p & 31;
        int y = ty0 + ly, x = tx0 + lx;

        size_t fi = (size_t)(b * 2) * plane + (size_t)y * WW + x;
        float fx = flowa[fi], fy = flowa[fi + plane];
        float X = (float)x + fx, Y = (float)y + fy;

        // border mask
        float mask = sigm(X + 0.5f) * (1.f - sigm(X - ((float)WW - 0.5f)))
                   * sigm(Y + 0.5f) * (1.f - sigm(Y - ((float)HH - 0.5f)));

        // warped backward flow -> occlusion
        float wf[2];
        bilin<2>(flowb, b, X, Y, wf);
        float mag = fx * fx + fy * fy + wf[0] * wf[0] + wf[1] * wf[1];
        float sx = fx + wf[0], sy = fy + wf[1];
        float d2 = sx * sx + sy * sy;
        float occ = 1.f - sigm(d2 - (0.01f * mag + 0.5f));
        mask *= occ;

        // data term
        float A = 0.f;
#pragma unroll
        for (int c = 0; c < 3; ++c) {
            float d = lds_a[c][ly + 2][lx + 2] - lds_w[c][ly + 2][lx + 2];
            A += d * d;
        }

        // smooth term (forward diffs, zero-padded at last col/row)
        float sm = 0.f;
        if (x < WW - 1) {
            float dfx = flowa[fi + 1] - fx;
            float dfy = flowa[fi + plane + 1] - fy;
            sm += dfx * dfx + dfy * dfy;
        }
        if (y < HH - 1) {
            float dfx = flowa[fi + WW] - fx;
            float dfy = flowa[fi + plane + WW] - fy;
            sm += dfx * dfx + dfy * dfy;
        }

        // gradient term: 5-tap derivative on imga and warped imgb
        float C = 0.f;
#pragma unroll
        for (int c = 0; c < 3; ++c) {
            float gha = T1 * (lds_a[c][ly + 2][lx + 1] - lds_a[c][ly + 2][lx + 3])
                      + T0 * (lds_a[c][ly + 2][lx + 4] - lds_a[c][ly + 2][lx]);
            float ghw = T1 * (lds_w[c][ly + 2][lx + 1] - lds_w[c][ly + 2][lx + 3])
                      + T0 * (lds_w[c][ly + 2][lx + 4] - lds_w[c][ly + 2][lx]);
            float d = gha - ghw;
            C += d * d;
            float gva = T1 * (lds_a[c][ly + 1][lx + 2] - lds_a[c][ly + 3][lx + 2])
                      + T0 * (lds_a[c][ly + 4][lx + 2] - lds_a[c][ly][lx + 2]);
            float gvw = T1 * (lds_w[c][ly + 1][lx + 2] - lds_w[c][ly + 3][lx + 2])
                      + T0 * (lds_w[c][ly + 4][lx + 2] - lds_w[c][ly][lx + 2]);
            d = gva - gvw;
            C += d * d;
        }

        local += sqrtf(A + 1e-5f) * mask            // ALPHA * data
               + sqrtf(sm + 1e-5f)                   // BETA * smooth
               + sqrtf(C + 1e-5f) * mask             // GAMMA * grad
               + 12.4f * (1.f - mask)                // MASK_COST * mask_term
               + sqrtf(d2 + 1e-5f) * mask;           // DELTA * fb contribution

        if (EPE) {
            float dx = fx - target[fi];
            float dy = fy - target[fi + plane];
            lepe += sqrtf(dx * dx + dy * dy);
        }
    }

    // ---- block reduction ----
#pragma unroll
    for (int off = 32; off > 0; off >>= 1) {
        local += __shfl_down(local, off);
        if (EPE) lepe += __shfl_down(lepe, off);
    }
    int wid = tid >> 6;
    if ((tid & 63) == 0) { red[wid] = local; red[4 + wid] = lepe; }
    __syncthreads();
    if (tid == 0) {
        atomicAdd(&acc[0], red[0] + red[1] + red[2] + red[3]);
        if (EPE) atomicAdd(&acc[1], red[4] + red[5] + red[6] + red[7]);
    }
}

__global__ void finalize_kernel(const float* __restrict__ acc, float* __restrict__ out) {
    out[0] = acc[0] / (float)BB;
    out[1] = acc[1] / (float)((size_t)BB * HH * WW);
}

extern "C" void kernel_launch(void* const* d_in, const int* in_sizes, int n_in,
                              void* d_out, int out_size, void* d_ws, size_t ws_size,
                              hipStream_t stream) {
    const float* flowf  = (const float*)d_in[0];
    const float* flowb  = (const float*)d_in[1];
    const float* img1   = (const float*)d_in[2];
    const float* img2   = (const float*)d_in[3];
    const float* target = (const float*)d_in[4];
    float* out = (float*)d_out;
    float* acc = (float*)d_ws;

    hipMemsetAsync(acc, 0, 2 * sizeof(float), stream);

    dim3 grid(WW / TILE, HH / TILE, BB);
    // forward: warp (flowb, img2) by flowf; compare against img1; +EPE vs target
    dir_kernel<true ><<<grid, 256, 0, stream>>>(flowf, flowb, img1, img2, target, acc);
    // backward: warp (flowf, img1) by flowb; compare against img2
    dir_kernel<false><<<grid, 256, 0, stream>>>(flowb, flowf, img2, img1, nullptr, acc);

    finalize_kernel<<<1, 1, 0, stream>>>(acc, out);
}